// Round 1
// baseline (671.266 us; speedup 1.0000x reference)
//
#include <hip/hip_runtime.h>

// Problem constants
constexpr int B  = 16;
constexpr int C  = 512;
constexpr int CC = 64;      // c = C/8
constexpr int N  = 4096;    // H*W

// Workspace layout (floats)
constexpr size_t QKV_OFF = 0;                         // [3][B][64][N] = 12,582,912
constexpr size_t S_OFF   = 12582912;                  // [B][64][64]   = 65,536
constexpr size_t WT_OFF  = 12648448;                  // [3][512][64]  = 98,304
constexpr size_t WOT_OFF = 12746752;                  // [64][512]     = 32,768
constexpr size_t MT_OFF  = 12779520;                  // [B][64][512]  = 524,288
// total 13,303,808 floats = 53.2 MB

// ---------------------------------------------------------------------------
// Prep: transpose weights so the GEMM inner loops read contiguous, wave-uniform
// rows (-> scalar s_load_dwordx16).  Wt[m][k][r] = W_m[r][k]; Wot[c][CO] = Wo[CO][c]
__global__ __launch_bounds__(256) void k_prep(
    const float* __restrict__ Wq, const float* __restrict__ Wk,
    const float* __restrict__ Wv, const float* __restrict__ Wo,
    float* __restrict__ wt, float* __restrict__ wot)
{
    int idx = blockIdx.x * 256 + threadIdx.x;   // 0..131071
    if (idx < 3 * C * CC) {
        int m   = idx / (C * CC);
        int rem = idx % (C * CC);               // k*64 + r
        int k = rem >> 6, r = rem & 63;
        const float* W = (m == 0) ? Wq : (m == 1) ? Wk : Wv;
        wt[idx] = W[r * C + k];
    } else {
        int i2 = idx - 3 * C * CC;              // cc*512 + co
        int cc = i2 >> 9, co = i2 & 511;
        wot[i2] = Wo[co * CC + cc];
    }
}

// ---------------------------------------------------------------------------
// QKV projection: per block: one (b, m in {Q,K,V}), 256 columns; each thread
// owns 1 column x all 64 output rows.  Weights stream through SGPRs.
__global__ __launch_bounds__(256) void k_qkv(
    const float* __restrict__ x, const float* __restrict__ wt,
    const float* __restrict__ bq, const float* __restrict__ bk,
    const float* __restrict__ bv, float* __restrict__ qkv)
{
    int bm = blockIdx.x;            // b*3 + m
    int b = bm / 3, m = bm % 3;
    int col = blockIdx.y * 256 + threadIdx.x;
    const float* Xb = x + (size_t)b * C * N;
    const float* w0 = wt + (size_t)m * C * CC;
    const float* bias = (m == 0) ? bq : (m == 1) ? bk : bv;

    float acc[64];
#pragma unroll
    for (int r = 0; r < 64; ++r) acc[r] = 0.f;

    for (int k = 0; k < C; ++k) {
        float xv = Xb[(size_t)k * N + col];
        const float* w = w0 + k * 64;           // wave-uniform -> s_load
#pragma unroll
        for (int r = 0; r < 64; ++r) acc[r] = fmaf(w[r], xv, acc[r]);
    }

    float* O = qkv + ((size_t)m * B + b) * (CC * N);
#pragma unroll
    for (int r = 0; r < 64; ++r) O[(size_t)r * N + col] = acc[r] + bias[r];
}

// ---------------------------------------------------------------------------
// Logits: S[b] += Q[b][:, n0:n0+64] @ Kresh[n0:n0+64, :]  (split-K atomics).
// Kresh[n, j] = Kflat[b, n*64 + j]  (the torch .view reshape, NOT a transpose).
__global__ __launch_bounds__(256) void k_logits(
    const float* __restrict__ qkv, float* __restrict__ S)
{
    int b  = blockIdx.x;        // 16
    int n0 = blockIdx.y * 64;   // 64 chunks
    __shared__ float Qs[64 * 68];   // [i][nn], pad 68 -> 2-way max (free)
    __shared__ float Ks[64 * 64];   // [nn][j], contiguous slice of Kflat

    const float* Qb = qkv + (size_t)b * (CC * N);
    const float* Kb = qkv + (size_t)(B + b) * (CC * N);
    int tid = threadIdx.x;

    for (int t = tid; t < 64 * 64; t += 256) {
        int i = t >> 6, nn = t & 63;
        Qs[i * 68 + nn] = Qb[(size_t)i * N + n0 + nn];
        Ks[t] = Kb[(size_t)n0 * 64 + t];
    }
    __syncthreads();

    int ti = tid >> 4, tj = tid & 15;
    int i0 = ti * 4, j0 = tj * 4;
    float acc[4][4] = {};
    for (int nn = 0; nn < 64; ++nn) {
        float4 kv = *reinterpret_cast<const float4*>(&Ks[nn * 64 + j0]);
        float qa[4];
#pragma unroll
        for (int a = 0; a < 4; ++a) qa[a] = Qs[(i0 + a) * 68 + nn];
#pragma unroll
        for (int a = 0; a < 4; ++a) {
            acc[a][0] = fmaf(qa[a], kv.x, acc[a][0]);
            acc[a][1] = fmaf(qa[a], kv.y, acc[a][1]);
            acc[a][2] = fmaf(qa[a], kv.z, acc[a][2]);
            acc[a][3] = fmaf(qa[a], kv.w, acc[a][3]);
        }
    }
    float* Sb = S + b * (CC * CC);
#pragma unroll
    for (int a = 0; a < 4; ++a)
#pragma unroll
        for (int bb = 0; bb < 4; ++bb)
            atomicAdd(&Sb[(i0 + a) * 64 + j0 + bb], acc[a][bb]);
}

// ---------------------------------------------------------------------------
// Softmax over rows of S[b] (64x64), then fold Wo:  Mt[b][d][CO] = sum_c Wo[CO,c]*attn[c,d]
__global__ __launch_bounds__(256) void k_softmax_m(
    const float* __restrict__ S, const float* __restrict__ wot,
    float* __restrict__ Mt)
{
    int b = blockIdx.x, chunk = blockIdx.y;   // 16 x 8
    __shared__ float A[64 * 65];
    int tid = threadIdx.x;
    const float* Sb = S + b * (CC * CC);

    for (int t = tid; t < 4096; t += 256) {
        int i = t >> 6, j = t & 63;
        A[i * 65 + j] = Sb[t];
    }
    __syncthreads();
    if (tid < 64) {
        float mx = -1e30f;
        for (int j = 0; j < 64; ++j) mx = fmaxf(mx, A[tid * 65 + j]);
        float sum = 0.f;
        for (int j = 0; j < 64; ++j) {
            float e = __expf(A[tid * 65 + j] - mx);
            A[tid * 65 + j] = e;
            sum += e;
        }
        float inv = 1.f / sum;
        for (int j = 0; j < 64; ++j) A[tid * 65 + j] *= inv;
    }
    __syncthreads();

    int co = chunk * 64 + (tid & 63);
    int e0 = (tid >> 6) * 16;
    float acc[16] = {};
    for (int cc = 0; cc < 64; ++cc) {
        float w = wot[cc * C + co];             // coalesced across lanes
#pragma unroll
        for (int ee = 0; ee < 16; ++ee)
            acc[ee] = fmaf(w, A[cc * 65 + e0 + ee], acc[ee]);
    }
    float* M = Mt + (size_t)b * (CC * C);
#pragma unroll
    for (int ee = 0; ee < 16; ++ee) M[(e0 + ee) * C + co] = acc[ee];
}

// ---------------------------------------------------------------------------
// Epilogue: out[b,CO,n] = gamma*( sum_e Mt[b][e][CO]*V[b,e,n] + bo[CO] ) + x[b,CO,n]
__global__ __launch_bounds__(256) void k_out(
    const float* __restrict__ qkv, const float* __restrict__ Mt,
    const float* __restrict__ x, const float* __restrict__ bo,
    const float* __restrict__ gamma, float* __restrict__ out)
{
    int b = blockIdx.x;                           // 16
    int co0 = blockIdx.y * 64;                    // 8 chunks
    int col = blockIdx.z * 256 + threadIdx.x;     // 16 tiles
    const float* V = qkv + (size_t)(2 * B + b) * (CC * N);
    const float* M = Mt + (size_t)b * (CC * C);
    float g = gamma[0];

    float acc[64];
#pragma unroll
    for (int r = 0; r < 64; ++r) acc[r] = 0.f;

    for (int e = 0; e < 64; ++e) {
        float vv = V[(size_t)e * N + col];
        const float* Me = M + e * C + co0;        // wave-uniform -> s_load
#pragma unroll
        for (int r = 0; r < 64; ++r) acc[r] = fmaf(Me[r], vv, acc[r]);
    }

    const float* xb = x + ((size_t)b * C + co0) * N;
    float* ob = out + ((size_t)b * C + co0) * N;
#pragma unroll
    for (int r = 0; r < 64; ++r)
        ob[(size_t)r * N + col] = fmaf(g, acc[r] + bo[co0 + r], xb[(size_t)r * N + col]);
}

// ---------------------------------------------------------------------------
extern "C" void kernel_launch(void* const* d_in, const int* in_sizes, int n_in,
                              void* d_out, int out_size, void* d_ws, size_t ws_size,
                              hipStream_t stream)
{
    const float* x     = (const float*)d_in[0];
    const float* Wq    = (const float*)d_in[1];
    const float* bq    = (const float*)d_in[2];
    const float* Wk    = (const float*)d_in[3];
    const float* bk    = (const float*)d_in[4];
    const float* Wv    = (const float*)d_in[5];
    const float* bv    = (const float*)d_in[6];
    const float* Wo    = (const float*)d_in[7];
    const float* bo    = (const float*)d_in[8];
    const float* gamma = (const float*)d_in[9];

    float* ws  = (float*)d_ws;
    float* qkv = ws + QKV_OFF;
    float* S   = ws + S_OFF;
    float* wt  = ws + WT_OFF;
    float* wot = ws + WOT_OFF;
    float* Mt  = ws + MT_OFF;

    hipMemsetAsync(S, 0, (size_t)B * CC * CC * sizeof(float), stream);
    k_prep<<<512, 256, 0, stream>>>(Wq, Wk, Wv, Wo, wt, wot);
    k_qkv<<<dim3(48, 16), 256, 0, stream>>>(x, wt, bq, bk, bv, qkv);
    k_logits<<<dim3(16, 64), 256, 0, stream>>>(qkv, S);
    k_softmax_m<<<dim3(16, 8), 256, 0, stream>>>(S, wot, Mt);
    k_out<<<dim3(16, 8, 16), 256, 0, stream>>>(qkv, Mt, x, bo, gamma, (float*)d_out);
}

// Round 2
// 422.029 us; speedup vs baseline: 1.5906x; 1.5906x over previous
//
#include <hip/hip_runtime.h>

typedef unsigned short ushortT;
typedef unsigned int uintT;
typedef __attribute__((ext_vector_type(8))) short short8;
typedef __attribute__((ext_vector_type(4))) float float4v;

// Problem constants
constexpr int B  = 16;
constexpr int C  = 512;
constexpr int CC = 64;      // c = C/8
constexpr int N  = 4096;    // H*W

// Workspace layout (float units)
// QK fp32 [2][16][64][4096]      : 8,388,608
// S  fp32 [16][64][64]           : 65,536
// Vt bf16 [16][4096][64] swizzled: 4,194,304 elem = 2,097,152 fl
// Mf bf16 [16][512][64] swizzled : 524,288 elem   = 262,144 fl
// Wh bf16 [8][192][64] swizzled  : 98,304 elem    = 49,152 fl
// Wl bf16 same                   : 49,152 fl
// Wot fp32 [64][512]             : 32,768 fl
// total 10,944,512 floats = 43.8 MB
constexpr size_t QK_OFF  = 0;
constexpr size_t S_OFF   = 8388608;
constexpr size_t VT_OFF  = 8454144;
constexpr size_t MF_OFF  = 10551296;
constexpr size_t WH_OFF  = 10813440;
constexpr size_t WL_OFF  = 10862592;
constexpr size_t WOT_OFF = 10911744;

// async global->LDS, 16B per lane; LDS dest = wave-uniform base + lane*16
#define GLL(lds, g) __builtin_amdgcn_global_load_lds( \
    (const __attribute__((address_space(1))) void*)(g), \
    (__attribute__((address_space(3))) void*)(lds), 16, 0, 0)

static __device__ __forceinline__ ushortT f2bf(float f) {
    uintT u = __float_as_uint(f);
    u = (u + 0x7fffu + ((u >> 16) & 1u)) >> 16;   // RNE
    return (ushortT)u;
}
static __device__ __forceinline__ float bf2f(ushortT h) {
    return __uint_as_float(((uintT)h) << 16);
}

// ---------------------------------------------------------------------------
// Weight prep: split W into bf16 hi/lo, laid out [ktile][192 rows][64 k] with
// per-row XOR chunk swizzle (16B chunk c stored at c ^ (row&7)) so that
// global_load_lds staging + ds_read_b128 frag reads are conflict-free.
// Also wot[cc][co] = Wo[co][cc] fp32 for the softmax-fold kernel.
__global__ __launch_bounds__(256) void k_prep_w(
    const float* __restrict__ Wq, const float* __restrict__ Wk,
    const float* __restrict__ Wv, const float* __restrict__ Wo,
    ushortT* __restrict__ wh, ushortT* __restrict__ wl, float* __restrict__ wot)
{
    int idx = blockIdx.x * 256 + threadIdx.x;   // 0..131071
    if (idx < 3 * CC * C) {                     // 98304
        int m = idx >> 9, k = idx & 511;        // m 0..191
        const float* W = (m < 64) ? Wq : (m < 128 ? Wk : Wv);
        float v = W[(m & 63) * C + k];
        ushortT h = f2bf(v);
        ushortT l = f2bf(v - bf2f(h));
        int kt = k >> 6, kk = k & 63;
        size_t off = ((size_t)(kt * 192 + m)) * 64 + (size_t)(((kk >> 3) ^ (m & 7)) * 8) + (kk & 7);
        wh[off] = h;
        wl[off] = l;
    } else {
        int i2 = idx - 3 * CC * C;              // cc*512 + co
        int cc = i2 >> 9, co = i2 & 511;
        wot[i2] = Wo[co * CC + cc];
    }
}

// ---------------------------------------------------------------------------
// QKV projection, split-bf16 MFMA:  D = Wh*Xh + Wl*Xh + Wh*Xl  (fp32 acc).
// Block: all 192 output rows x 64 spatial cols, K=512 in 8 tiles of 64.
// X slab is converted/transposed into LDS (Bh=hi, Bl=lo) per k-tile.
// Q,K stored fp32 [2][B][64][N]; V stored bf16 transposed-swizzled Vt[b][n][64].
__global__ __launch_bounds__(256) void k_qkv(
    const float* __restrict__ x,
    const ushortT* __restrict__ wh, const ushortT* __restrict__ wl,
    const float* __restrict__ bq, const float* __restrict__ bk,
    const float* __restrict__ bv,
    float* __restrict__ qk, ushortT* __restrict__ vt)
{
    __shared__ ushortT As[192 * 64];   // 24 KB (weights, swizzled rows of 128B)
    __shared__ ushortT Bh[64 * 64];    // 8 KB  (x hi, [n][k] swizzled)
    __shared__ ushortT Bl[64 * 64];    // 8 KB  (x lo)

    const int tid  = threadIdx.x;
    const int n0   = blockIdx.x * 64;     // 64 col-tiles
    const int b    = blockIdx.y;
    const int lane = tid & 63;
    const int wv   = tid >> 6;            // 4 waves, wave tile 48m x 64n
    const int L15  = lane & 15, Lq = lane >> 4;

    const int nl    = tid & 63;           // staging: this thread's column
    const int kbase = tid >> 6;           // staging: k offset 0..3

    float4v acc[3][4];
    const float4v vzero = {0.f, 0.f, 0.f, 0.f};
#pragma unroll
    for (int mi = 0; mi < 3; ++mi)
#pragma unroll
        for (int ni = 0; ni < 4; ++ni) acc[mi][ni] = vzero;

    for (int kt = 0; kt < 8; ++kt) {
        // ---- stage X slab [64k][64n] -> Bh/Bl (transpose + split-convert) ----
        const float* xs = x + ((size_t)(b * C + kt * 64)) * N + n0 + nl;
#pragma unroll
        for (int it = 0; it < 16; ++it) {
            int kk = kbase + it * 4;
            float v = xs[(size_t)kk * N];
            ushortT h = f2bf(v);
            ushortT l = f2bf(v - bf2f(h));
            int idx = nl * 64 + (((kk >> 3) ^ (nl & 7)) * 8) + (kk & 7);
            Bh[idx] = h;
            Bl[idx] = l;
        }
        // ---- stage A <- Wh[kt] (24576 B, 6 chunks/thread) ----
        {
            const char* src = (const char*)wh + (size_t)kt * 24576;
#pragma unroll
            for (int i = 0; i < 6; ++i) {
                int off = i * 4096 + tid * 16;
                GLL((char*)As + off, src + off);
            }
        }
        __syncthreads();
        // ---- phase 1: Wh*Xh and Wh*Xl ----
#pragma unroll
        for (int s = 0; s < 2; ++s) {
            short8 fbh[4], fbl[4];
#pragma unroll
            for (int ni = 0; ni < 4; ++ni) {
                int row = ni * 16 + L15;
                int off = row * 64 + ((4 * s + Lq) ^ (row & 7)) * 8;
                fbh[ni] = *(const short8*)&Bh[off];
                fbl[ni] = *(const short8*)&Bl[off];
            }
#pragma unroll
            for (int mi = 0; mi < 3; ++mi) {
                int rm = 48 * wv + mi * 16 + L15;
                short8 a = *(const short8*)&As[rm * 64 + (((4 * s + Lq) ^ (rm & 7)) * 8)];
#pragma unroll
                for (int ni = 0; ni < 4; ++ni)
                    acc[mi][ni] = __builtin_amdgcn_mfma_f32_16x16x32_bf16(a, fbh[ni], acc[mi][ni], 0, 0, 0);
#pragma unroll
                for (int ni = 0; ni < 4; ++ni)
                    acc[mi][ni] = __builtin_amdgcn_mfma_f32_16x16x32_bf16(a, fbl[ni], acc[mi][ni], 0, 0, 0);
            }
        }
        __syncthreads();
        // ---- restage A <- Wl[kt] ----
        {
            const char* src = (const char*)wl + (size_t)kt * 24576;
#pragma unroll
            for (int i = 0; i < 6; ++i) {
                int off = i * 4096 + tid * 16;
                GLL((char*)As + off, src + off);
            }
        }
        __syncthreads();
        // ---- phase 2: Wl*Xh ----
#pragma unroll
        for (int s = 0; s < 2; ++s) {
            short8 fbh[4];
#pragma unroll
            for (int ni = 0; ni < 4; ++ni) {
                int row = ni * 16 + L15;
                fbh[ni] = *(const short8*)&Bh[row * 64 + ((4 * s + Lq) ^ (row & 7)) * 8];
            }
#pragma unroll
            for (int mi = 0; mi < 3; ++mi) {
                int rm = 48 * wv + mi * 16 + L15;
                short8 a = *(const short8*)&As[rm * 64 + (((4 * s + Lq) ^ (rm & 7)) * 8)];
#pragma unroll
                for (int ni = 0; ni < 4; ++ni)
                    acc[mi][ni] = __builtin_amdgcn_mfma_f32_16x16x32_bf16(a, fbh[ni], acc[mi][ni], 0, 0, 0);
            }
        }
        __syncthreads();
    }

    // ---- epilogue: rows 0-63 -> Q (fp32), 64-127 -> K (fp32), 128-191 -> V (bf16 Vt) ----
#pragma unroll
    for (int mi = 0; mi < 3; ++mi) {
        int rbase = 48 * wv + mi * 16;     // 16-aligned, frag fits one 64-block
        int type = rbase >> 6;             // 0=Q 1=K 2=V (uniform per frag)
#pragma unroll
        for (int ni = 0; ni < 4; ++ni) {
            int col = n0 + ni * 16 + L15;
            float4v v4 = acc[mi][ni];
#pragma unroll
            for (int reg = 0; reg < 4; ++reg) {
                int rl = (rbase + Lq * 4 + reg) & 63;
                float val = v4[reg];
                if (type == 0) {
                    qk[((size_t)(b * 64 + rl)) * N + col] = val + bq[rl];
                } else if (type == 1) {
                    qk[((size_t)((16 + b) * 64 + rl)) * N + col] = val + bk[rl];
                } else {
                    ushortT bb = f2bf(val + bv[rl]);
                    size_t off = ((size_t)(b * N + col)) * 64 + (((rl >> 3) ^ (col & 7)) * 8) + (rl & 7);
                    vt[off] = bb;
                }
            }
        }
    }
}

// ---------------------------------------------------------------------------
// Logits: S[b] += Q[b][:, n0:n0+64] @ Kresh[n0:n0+64, :]  (split-K atomics).
// Kresh[n, j] = Kflat[b, n*64 + j]  (the torch .view reshape, NOT a transpose).
__global__ __launch_bounds__(256) void k_logits(
    const float* __restrict__ qk, float* __restrict__ S)
{
    int b  = blockIdx.x;        // 16
    int n0 = blockIdx.y * 64;   // 64 chunks
    __shared__ float Qs[64 * 68];
    __shared__ float Ks[64 * 64];

    const float* Qb = qk + (size_t)b * (CC * N);
    const float* Kb = qk + (size_t)(16 + b) * (CC * N);
    int tid = threadIdx.x;

    for (int t = tid; t < 64 * 64; t += 256) {
        int i = t >> 6, nn = t & 63;
        Qs[i * 68 + nn] = Qb[(size_t)i * N + n0 + nn];
        Ks[t] = Kb[(size_t)n0 * 64 + t];
    }
    __syncthreads();

    int ti = tid >> 4, tj = tid & 15;
    int i0 = ti * 4, j0 = tj * 4;
    float accl[4][4] = {};
    for (int nn = 0; nn < 64; ++nn) {
        float4 kv = *reinterpret_cast<const float4*>(&Ks[nn * 64 + j0]);
        float qa[4];
#pragma unroll
        for (int a = 0; a < 4; ++a) qa[a] = Qs[(i0 + a) * 68 + nn];
#pragma unroll
        for (int a = 0; a < 4; ++a) {
            accl[a][0] = fmaf(qa[a], kv.x, accl[a][0]);
            accl[a][1] = fmaf(qa[a], kv.y, accl[a][1]);
            accl[a][2] = fmaf(qa[a], kv.z, accl[a][2]);
            accl[a][3] = fmaf(qa[a], kv.w, accl[a][3]);
        }
    }
    float* Sb = S + b * (CC * CC);
#pragma unroll
    for (int a = 0; a < 4; ++a)
#pragma unroll
        for (int bb = 0; bb < 4; ++bb)
            atomicAdd(&Sb[(i0 + a) * 64 + j0 + bb], accl[a][bb]);
}

// ---------------------------------------------------------------------------
// Softmax over rows of S[b] (64x64), then fold Wo:
//   Mf[b][co][e] = sum_c Wo[co,c] * attn[c,e]  -> bf16, swizzled rows of 128B.
__global__ __launch_bounds__(256) void k_softmax_m(
    const float* __restrict__ S, const float* __restrict__ wot,
    ushortT* __restrict__ mf)
{
    int b = blockIdx.x, chunk = blockIdx.y;   // 16 x 8
    __shared__ float A[64 * 65];
    int tid = threadIdx.x;
    const float* Sb = S + b * (CC * CC);

    for (int t = tid; t < 4096; t += 256) A[(t >> 6) * 65 + (t & 63)] = Sb[t];
    __syncthreads();
    if (tid < 64) {
        float mx = -1e30f;
        for (int j = 0; j < 64; ++j) mx = fmaxf(mx, A[tid * 65 + j]);
        float sum = 0.f;
        for (int j = 0; j < 64; ++j) {
            float e = __expf(A[tid * 65 + j] - mx);
            A[tid * 65 + j] = e;
            sum += e;
        }
        float inv = 1.f / sum;
        for (int j = 0; j < 64; ++j) A[tid * 65 + j] *= inv;
    }
    __syncthreads();

    int co = chunk * 64 + (tid & 63);
    int e0 = (tid >> 6) * 16;
    float acc[16] = {};
    for (int cc = 0; cc < 64; ++cc) {
        float w = wot[cc * C + co];
#pragma unroll
        for (int ee = 0; ee < 16; ++ee)
            acc[ee] = fmaf(w, A[cc * 65 + e0 + ee], acc[ee]);
    }
#pragma unroll
    for (int d = 0; d < 2; ++d) {
        int c = (e0 >> 3) + d;               // logical 8-elem chunk
        uintT p0 = (uintT)f2bf(acc[d * 8 + 0]) | ((uintT)f2bf(acc[d * 8 + 1]) << 16);
        uintT p1 = (uintT)f2bf(acc[d * 8 + 2]) | ((uintT)f2bf(acc[d * 8 + 3]) << 16);
        uintT p2 = (uintT)f2bf(acc[d * 8 + 4]) | ((uintT)f2bf(acc[d * 8 + 5]) << 16);
        uintT p3 = (uintT)f2bf(acc[d * 8 + 6]) | ((uintT)f2bf(acc[d * 8 + 7]) << 16);
        uint4 pk = make_uint4(p0, p1, p2, p3);
        size_t off = ((size_t)(b * C + co)) * 64 + (size_t)((c ^ (co & 7)) * 8);
        *(uint4*)&mf[off] = pk;
    }
}

// ---------------------------------------------------------------------------
// Output: out[b,co,n] = gamma*( sum_e Mf[co,e]*Vt[n,e] + bo[co] ) + x[b,co,n]
// MFMA, K=64, A = Mf tile (64 rows), B = Vt tile (256 rows), both GLL-staged.
__global__ __launch_bounds__(256) void k_out(
    const ushortT* __restrict__ vt, const ushortT* __restrict__ mf,
    const float* __restrict__ x, const float* __restrict__ bo,
    const float* __restrict__ gamma, float* __restrict__ out)
{
    __shared__ ushortT As[64 * 64];    // 8 KB  Mf rows co0..co0+64
    __shared__ ushortT Bs[256 * 64];   // 32 KB Vt rows n0..n0+256

    int b = blockIdx.x, ct = blockIdx.y, nt = blockIdx.z;
    int co0 = ct * 64, n0 = nt * 256;
    int tid = threadIdx.x;
    const char* asrc = (const char*)mf + ((size_t)(b * C + co0)) * 128;
    const char* bsrc = (const char*)vt + ((size_t)(b * N + n0)) * 128;
#pragma unroll
    for (int i = 0; i < 2; ++i) {
        int off = i * 4096 + tid * 16;
        GLL((char*)As + off, asrc + off);
    }
#pragma unroll
    for (int i = 0; i < 8; ++i) {
        int off = i * 4096 + tid * 16;
        GLL((char*)Bs + off, bsrc + off);
    }
    __syncthreads();

    int lane = tid & 63, wv = tid >> 6;
    int L15 = lane & 15, Lq = lane >> 4;
    float4v acc[4][4];
    const float4v vzero = {0.f, 0.f, 0.f, 0.f};
#pragma unroll
    for (int mi = 0; mi < 4; ++mi)
#pragma unroll
        for (int ni = 0; ni < 4; ++ni) acc[mi][ni] = vzero;

#pragma unroll
    for (int s = 0; s < 2; ++s) {
        short8 fb[4];
#pragma unroll
        for (int ni = 0; ni < 4; ++ni) {
            int row = wv * 64 + ni * 16 + L15;
            fb[ni] = *(const short8*)&Bs[row * 64 + ((4 * s + Lq) ^ (row & 7)) * 8];
        }
#pragma unroll
        for (int mi = 0; mi < 4; ++mi) {
            int rm = mi * 16 + L15;
            short8 a = *(const short8*)&As[rm * 64 + ((4 * s + Lq) ^ (rm & 7)) * 8];
#pragma unroll
            for (int ni = 0; ni < 4; ++ni)
                acc[mi][ni] = __builtin_amdgcn_mfma_f32_16x16x32_bf16(a, fb[ni], acc[mi][ni], 0, 0, 0);
        }
    }

    float g = gamma[0];
#pragma unroll
    for (int mi = 0; mi < 4; ++mi) {
        int cob = co0 + mi * 16 + Lq * 4;
#pragma unroll
        for (int ni = 0; ni < 4; ++ni) {
            int col = n0 + wv * 64 + ni * 16 + L15;
            float4v v4 = acc[mi][ni];
#pragma unroll
            for (int reg = 0; reg < 4; ++reg) {
                int c2 = cob + reg;
                size_t idx = ((size_t)(b * C + c2)) * N + col;
                out[idx] = fmaf(g, v4[reg] + bo[c2], x[idx]);
            }
        }
    }
}

// ---------------------------------------------------------------------------
extern "C" void kernel_launch(void* const* d_in, const int* in_sizes, int n_in,
                              void* d_out, int out_size, void* d_ws, size_t ws_size,
                              hipStream_t stream)
{
    const float* x     = (const float*)d_in[0];
    const float* Wq    = (const float*)d_in[1];
    const float* bq    = (const float*)d_in[2];
    const float* Wk    = (const float*)d_in[3];
    const float* bk    = (const float*)d_in[4];
    const float* Wv    = (const float*)d_in[5];
    const float* bv    = (const float*)d_in[6];
    const float* Wo    = (const float*)d_in[7];
    const float* bo    = (const float*)d_in[8];
    const float* gamma = (const float*)d_in[9];

    float* ws   = (float*)d_ws;
    float* qk   = ws + QK_OFF;
    float* S    = ws + S_OFF;
    ushortT* vt = (ushortT*)(ws + VT_OFF);
    ushortT* mf = (ushortT*)(ws + MF_OFF);
    ushortT* wh = (ushortT*)(ws + WH_OFF);
    ushortT* wl = (ushortT*)(ws + WL_OFF);
    float* wot  = ws + WOT_OFF;

    hipMemsetAsync(S, 0, (size_t)B * CC * CC * sizeof(float), stream);
    k_prep_w<<<512, 256, 0, stream>>>(Wq, Wk, Wv, Wo, wh, wl, wot);
    k_qkv<<<dim3(64, 16), 256, 0, stream>>>(x, wh, wl, bq, bk, bv, qk, vt);
    k_logits<<<dim3(16, 64), 256, 0, stream>>>(qk, S);
    k_softmax_m<<<dim3(16, 8), 256, 0, stream>>>(S, wot, mf);
    k_out<<<dim3(16, 8, 16), 256, 0, stream>>>(vt, mf, x, bo, gamma, (float*)d_out);
}